// Round 1
// baseline (143.198 us; speedup 1.0000x reference)
//
#include <hip/hip_runtime.h>

#define NSEQ 16
#define HID 1024
#define HV (HID / 4)      // float4 per row = 256 (== threads per block)
#define TPB 256
#define MAXCHUNKS 128

__device__ __forceinline__ bool lens_is64(const void* lens) {
    // Lengths are positive and < 2^31. If stored as little-endian int64,
    // 32-bit word 1 is the high half of lens[0] == 0. If int32, word 1 is
    // lens[1] > 0.
    return ((const int*)lens)[1] == 0;
}

__device__ __forceinline__ long long seg_len(const void* lens, int i, bool is64) {
    return is64 ? ((const long long*)lens)[i] : (long long)((const int*)lens)[i];
}

__device__ __forceinline__ float4 f4add(float4 a, float4 b) {
    return make_float4(a.x + b.x, a.y + b.y, a.z + b.z, a.w + b.w);
}

// Stage 1: block b = s*chunks + c sums its token slab into ws[b][HID].
__global__ void __launch_bounds__(TPB) seg_partial(
    const float* __restrict__ x, const void* __restrict__ lens,
    float* __restrict__ ws, int chunks) {
    int b = blockIdx.x;
    int s = b / chunks;
    int c = b - s * chunks;
    bool is64 = lens_is64(lens);
    long long off = 0;
    for (int i = 0; i < s; ++i) off += seg_len(lens, i, is64);
    long long len = seg_len(lens, s, is64);
    long long t0 = off + len * c / chunks;
    long long t1 = off + len * (c + 1) / chunks;
    int tid = threadIdx.x;

    const float4* xv = (const float4*)x + tid;
    float4 a0 = make_float4(0.f, 0.f, 0.f, 0.f);
    float4 a1 = a0, a2 = a0, a3 = a0;
    long long t = t0;
    for (; t + 4 <= t1; t += 4) {
        float4 v0 = xv[(t + 0) * HV];
        float4 v1 = xv[(t + 1) * HV];
        float4 v2 = xv[(t + 2) * HV];
        float4 v3 = xv[(t + 3) * HV];
        a0 = f4add(a0, v0);
        a1 = f4add(a1, v1);
        a2 = f4add(a2, v2);
        a3 = f4add(a3, v3);
    }
    for (; t < t1; ++t) a0 = f4add(a0, xv[t * HV]);
    float4 acc = f4add(f4add(a0, a1), f4add(a2, a3));
    ((float4*)ws)[(long long)b * HV + tid] = acc;
}

// Stage 2: one block per seq reduces its chunk partials and divides by len.
__global__ void __launch_bounds__(TPB) seg_finish(
    const float* __restrict__ ws, const void* __restrict__ lens,
    float* __restrict__ out, int chunks) {
    int s = blockIdx.x;
    int tid = threadIdx.x;
    bool is64 = lens_is64(lens);
    float inv = 1.0f / (float)seg_len(lens, s, is64);
    const float4* wv = (const float4*)ws + (long long)s * chunks * HV + tid;
    float4 acc = make_float4(0.f, 0.f, 0.f, 0.f);
    for (int c = 0; c < chunks; ++c) acc = f4add(acc, wv[(long long)c * HV]);
    float4 r = make_float4(acc.x * inv, acc.y * inv, acc.z * inv, acc.w * inv);
    ((float4*)out)[(long long)s * HV + tid] = r;
}

// Fallback if ws is too small: atomic accumulate of pre-scaled partials.
__global__ void __launch_bounds__(TPB) seg_atomic(
    const float* __restrict__ x, const void* __restrict__ lens,
    float* __restrict__ out, int chunks) {
    int b = blockIdx.x;
    int s = b / chunks;
    int c = b - s * chunks;
    bool is64 = lens_is64(lens);
    long long off = 0;
    for (int i = 0; i < s; ++i) off += seg_len(lens, i, is64);
    long long len = seg_len(lens, s, is64);
    long long t0 = off + len * c / chunks;
    long long t1 = off + len * (c + 1) / chunks;
    int tid = threadIdx.x;
    const float4* xv = (const float4*)x + tid;
    float4 acc = make_float4(0.f, 0.f, 0.f, 0.f);
    for (long long t = t0; t < t1; ++t) acc = f4add(acc, xv[t * HV]);
    float inv = 1.0f / (float)len;
    float* o = out + (long long)s * HID + tid * 4;
    atomicAdd(o + 0, acc.x * inv);
    atomicAdd(o + 1, acc.y * inv);
    atomicAdd(o + 2, acc.z * inv);
    atomicAdd(o + 3, acc.w * inv);
}

extern "C" void kernel_launch(void* const* d_in, const int* in_sizes, int n_in,
                              void* d_out, int out_size, void* d_ws, size_t ws_size,
                              hipStream_t stream) {
    const float* x = (const float*)d_in[0];
    const void* lens = d_in[1];
    float* out = (float*)d_out;

    size_t per_chunk = (size_t)NSEQ * HID * sizeof(float);  // 64 KiB per chunk layer
    int chunks = (int)(ws_size / per_chunk);
    if (chunks > MAXCHUNKS) chunks = MAXCHUNKS;

    if (chunks >= 1) {
        seg_partial<<<dim3(NSEQ * chunks), dim3(TPB), 0, stream>>>(
            x, lens, (float*)d_ws, chunks);
        seg_finish<<<dim3(NSEQ), dim3(TPB), 0, stream>>>(
            (const float*)d_ws, lens, out, chunks);
    } else {
        hipMemsetAsync(d_out, 0, (size_t)out_size * sizeof(float), stream);
        seg_atomic<<<dim3(NSEQ * 64), dim3(TPB), 0, stream>>>(x, lens, out, 64);
    }
}

// Round 2
// 101.238 us; speedup vs baseline: 1.4145x; 1.4145x over previous
//
#include <hip/hip_runtime.h>

#define NSEQ 16
#define HID 1024
#define HV (HID / 4)      // float4 per row = 256
#define TPB 256
#define TPB2 1024
#define MAXCHUNKS 128

typedef float f4 __attribute__((ext_vector_type(4)));

__device__ __forceinline__ bool lens_is64(const void* lens) {
    // Positive lengths < 2^31: little-endian int64 => word1 (high half of
    // lens[0]) == 0; int32 storage => word1 == lens[1] > 0.
    return ((const int*)lens)[1] == 0;
}

__device__ __forceinline__ long long seg_len(const void* lens, int i, bool is64) {
    return is64 ? ((const long long*)lens)[i] : (long long)((const int*)lens)[i];
}

// Stage 1: block b = s*chunks + c sums its token slab into ws[b][HID].
__global__ void __launch_bounds__(TPB) seg_partial(
    const float* __restrict__ x, const void* __restrict__ lens,
    float* __restrict__ ws, int chunks) {
    int b = blockIdx.x;
    int s = b / chunks;
    int c = b - s * chunks;
    bool is64 = lens_is64(lens);
    long long off = 0;
    for (int i = 0; i < s; ++i) off += seg_len(lens, i, is64);
    long long len = seg_len(lens, s, is64);
    long long t0 = off + len * c / chunks;
    long long t1 = off + len * (c + 1) / chunks;
    int rows = (int)(t1 - t0);
    int tid = threadIdx.x;

    const f4* p = (const f4*)x + (size_t)t0 * HV + tid;
    f4 a0 = (f4)0.f, a1 = (f4)0.f, a2 = (f4)0.f, a3 = (f4)0.f;
    int r = 0;
    for (; r + 4 <= rows; r += 4) {
        // two-phase: issue all 4 dwordx4 loads before any use; nt to skip
        // cache allocation on the 512 MB one-shot stream
        f4 v0 = __builtin_nontemporal_load(p + 0 * HV);
        f4 v1 = __builtin_nontemporal_load(p + 1 * HV);
        f4 v2 = __builtin_nontemporal_load(p + 2 * HV);
        f4 v3 = __builtin_nontemporal_load(p + 3 * HV);
        p += 4 * HV;
        a0 += v0;
        a1 += v1;
        a2 += v2;
        a3 += v3;
    }
    for (; r < rows; ++r) {
        a0 += __builtin_nontemporal_load(p);
        p += HV;
    }
    f4 acc = (a0 + a1) + (a2 + a3);
    ((f4*)ws)[(size_t)b * HV + tid] = acc;
}

// Stage 2: one 1024-thread block per seq; 4 chunk-groups in parallel,
// LDS tree-reduce, divide by len, write out.
__global__ void __launch_bounds__(TPB2) seg_finish(
    const float* __restrict__ ws, const void* __restrict__ lens,
    float* __restrict__ out, int chunks) {
    __shared__ f4 red[TPB2];
    int s = blockIdx.x;
    int tid = threadIdx.x;
    int col = tid & (HV - 1);   // 0..255 float4 column
    int q = tid >> 8;           // 0..3 chunk group
    bool is64 = lens_is64(lens);
    float inv = 1.0f / (float)seg_len(lens, s, is64);

    const f4* wv = (const f4*)ws + (size_t)s * chunks * HV + col;
    f4 acc = (f4)0.f;
    for (int c = q; c < chunks; c += 4) acc += wv[(size_t)c * HV];
    red[tid] = acc;
    __syncthreads();
    if (tid < 512) red[tid] += red[tid + 512];
    __syncthreads();
    if (tid < 256) {
        f4 r = (red[tid] + red[tid + 256]) * inv;
        ((f4*)out)[(size_t)s * HV + tid] = r;
    }
}

// Fallback if ws is too small: atomic accumulate of pre-scaled partials.
__global__ void __launch_bounds__(TPB) seg_atomic(
    const float* __restrict__ x, const void* __restrict__ lens,
    float* __restrict__ out, int chunks) {
    int b = blockIdx.x;
    int s = b / chunks;
    int c = b - s * chunks;
    bool is64 = lens_is64(lens);
    long long off = 0;
    for (int i = 0; i < s; ++i) off += seg_len(lens, i, is64);
    long long len = seg_len(lens, s, is64);
    long long t0 = off + len * c / chunks;
    long long t1 = off + len * (c + 1) / chunks;
    int tid = threadIdx.x;
    const f4* p = (const f4*)x + (size_t)t0 * HV + tid;
    f4 acc = (f4)0.f;
    for (long long t = t0; t < t1; ++t) {
        acc += *p;
        p += HV;
    }
    float inv = 1.0f / (float)len;
    float* o = out + (size_t)s * HID + tid * 4;
    atomicAdd(o + 0, acc.x * inv);
    atomicAdd(o + 1, acc.y * inv);
    atomicAdd(o + 2, acc.z * inv);
    atomicAdd(o + 3, acc.w * inv);
}

extern "C" void kernel_launch(void* const* d_in, const int* in_sizes, int n_in,
                              void* d_out, int out_size, void* d_ws, size_t ws_size,
                              hipStream_t stream) {
    const float* x = (const float*)d_in[0];
    const void* lens = d_in[1];
    float* out = (float*)d_out;

    size_t per_chunk = (size_t)NSEQ * HID * sizeof(float);  // 64 KiB per chunk layer
    int chunks = (int)(ws_size / per_chunk);
    if (chunks > MAXCHUNKS) chunks = MAXCHUNKS;

    if (chunks >= 1) {
        seg_partial<<<dim3(NSEQ * chunks), dim3(TPB), 0, stream>>>(
            x, lens, (float*)d_ws, chunks);
        seg_finish<<<dim3(NSEQ), dim3(TPB2), 0, stream>>>(
            (const float*)d_ws, lens, out, chunks);
    } else {
        hipMemsetAsync(d_out, 0, (size_t)out_size * sizeof(float), stream);
        seg_atomic<<<dim3(NSEQ * 64), dim3(TPB), 0, stream>>>(x, lens, out, 64);
    }
}